// Round 4
// baseline (209.964 us; speedup 1.0000x reference)
//
#include <hip/hip_runtime.h>
#include <hip/hip_cooperative_groups.h>

namespace cg = cooperative_groups;

// EncoderBlock, fused cooperative kernel with BALANCED 128x128 tiles:
//   gather(x, idx) -> per-(o, 128-batch-tile) GEMM (128x128 @ K=512) + bias
//   -> partial BN stats -> grid.sync -> BN finalize -> SiLU -> fp32 out.
// Grid 256 blocks x 1024 threads (16 waves, 4/SIMD; 1 block/CU, all CUs).
// Balanced tiles halve staged bytes vs the 512x32 BN-local design
// (272 MB -> 134 MB through L2/LLC). K-loop: depth-2 register prefetch,
// double-buffered LDS, ONE raw s_barrier per step (lgkmcnt(0) only -- global
// prefetch loads stay in flight across barriers, T4).

typedef __attribute__((ext_vector_type(8))) __bf16 bf16x8;
typedef __attribute__((ext_vector_type(4))) __bf16 bf16x4;
typedef __attribute__((ext_vector_type(4))) float  f32x4;

#define FEAT 8192
#define LDA  40              // LDS row stride (bf16): 80B, 16B-aligned

#define PIPE_BARRIER() do { \
    __builtin_amdgcn_sched_barrier(0); \
    asm volatile("s_waitcnt lgkmcnt(0)" ::: "memory"); \
    __builtin_amdgcn_s_barrier(); \
    __builtin_amdgcn_sched_barrier(0); \
} while (0)

__global__ __launch_bounds__(1024, 4)
void fused_encoder_coop(const float* __restrict__ x, const float* __restrict__ W,
                        const float* __restrict__ bias, const float* __restrict__ gamma,
                        const float* __restrict__ beta, const int* __restrict__ idxp,
                        float* __restrict__ out, float* __restrict__ psum,
                        float* __restrict__ psq)
{
    __shared__ alignas(16) __bf16 Alds[2][128 * LDA];   // 2 x 10 KiB
    __shared__ alignas(16) __bf16 Blds[2][128 * LDA];   // 2 x 10 KiB
    __shared__ float Sred[4][128];
    __shared__ float Qred[4][128];
    __shared__ float sscale[128];
    __shared__ float sshift[128];

    // XCD-aware decode: 4 batch-tiles of one o share an XCD (W[o] panel +
    // psum/psq exchange stay XCD-local).
    const int bid = blockIdx.x;
    const int o   = ((bid >> 5) << 3) | (bid & 7);
    const int bt  = (bid >> 3) & 3;
    const int b0  = bt * 128;

    const int tid  = threadIdx.x;
    const int wave = tid >> 6;          // 0..15
    const int lane = tid & 63;
    const int wr   = wave >> 2;         // 0..3: rows wr*32..+31
    const int wc   = wave & 3;          // 0..3: cols wc*32..+31
    const int lam  = lane & 15;
    const int quad = lane >> 4;

    int rsel[4];
#pragma unroll
    for (int k = 0; k < 4; ++k) rsel[k] = idxp[o * 4 + k];

    const f32x4 zero4 = {0.f, 0.f, 0.f, 0.f};
    f32x4 acc[2][2];
#pragma unroll
    for (int mi = 0; mi < 2; ++mi)
#pragma unroll
        for (int ni = 0; ni < 2; ++ni) acc[mi][ni] = zero4;

    // A staging: 8 threads/row, 4 floats each (128 rows x 32 k)
    const int m_a = tid >> 3;           // 0..127
    const int ca  = (tid & 7) * 4;      // 0..28
    // B staging: 1 task/thread: 4 k-strided scalars (coalesced over e)
    const int e_b = tid & 127;
    const int dgb = tid >> 7;           // 0..7 -> k-offset dgb*4

    f32x4 sA0, sA1, sB0, sB1;

    auto load_stage = [&](f32x4& SA, f32x4& SB, const int kkc) {
        const int kidx = kkc >> 2;
        const int d0   = (kkc & 3) * 32;
        SA = *(const f32x4*)(x + (((b0 + m_a) * 64 + rsel[kidx]) * 128 + d0 + ca));
        const float* wp = W + (((o * 4 + kidx) * 128 + d0 + dgb * 4) * 128 + e_b);
        f32x4 t;
        t[0] = wp[0]; t[1] = wp[128]; t[2] = wp[256]; t[3] = wp[384];
        SB = t;
    };

    auto store_stage = [&](const f32x4& SA, const f32x4& SB, const int buf) {
        bf16x4 pa, pb;
#pragma unroll
        for (int j = 0; j < 4; ++j) { pa[j] = (__bf16)SA[j]; pb[j] = (__bf16)SB[j]; }
        *(bf16x4*)&Alds[buf][m_a * LDA + ca]       = pa;
        *(bf16x4*)&Blds[buf][e_b * LDA + dgb * 4]  = pb;
    };

    auto compute = [&](const int buf) {
        bf16x8 af[2], bfr[2];
#pragma unroll
        for (int mi = 0; mi < 2; ++mi)
            af[mi] = *(const bf16x8*)&Alds[buf][(wr * 32 + mi * 16 + lam) * LDA + quad * 8];
#pragma unroll
        for (int ni = 0; ni < 2; ++ni)
            bfr[ni] = *(const bf16x8*)&Blds[buf][(wc * 32 + ni * 16 + lam) * LDA + quad * 8];
#pragma unroll
        for (int mi = 0; mi < 2; ++mi)
#pragma unroll
            for (int ni = 0; ni < 2; ++ni)
                acc[mi][ni] = __builtin_amdgcn_mfma_f32_16x16x32_bf16(
                    af[mi], bfr[ni], acc[mi][ni], 0, 0, 0);
    };

    // ---- pipeline: data kk lives in stage/buf (kk & 1) ----
    load_stage(sA0, sB0, 0);
    load_stage(sA1, sB1, 1);
    store_stage(sA0, sB0, 0);   // vmcnt waits stage-0 only; stage-1 in flight
    PIPE_BARRIER();

#pragma unroll
    for (int kk = 0; kk < 16; ++kk) {
        if (kk + 2 < 16) {
            if ((kk & 1) == 0) load_stage(sA0, sB0, kk + 2);
            else               load_stage(sA1, sB1, kk + 2);
        }
        __builtin_amdgcn_sched_barrier(0);
        compute(kk & 1);
        if (kk + 1 < 16) {
            if ((kk & 1) == 0) store_stage(sA1, sB1, 1);
            else               store_stage(sA0, sB0, 0);
            PIPE_BARRIER();
        }
    }

    // ---- bias ----
    float bvals[2];
#pragma unroll
    for (int ni = 0; ni < 2; ++ni)
        bvals[ni] = bias[o * 128 + wc * 32 + ni * 16 + lam];
#pragma unroll
    for (int mi = 0; mi < 2; ++mi)
#pragma unroll
        for (int ni = 0; ni < 2; ++ni)
#pragma unroll
            for (int rr = 0; rr < 4; ++rr) acc[mi][ni][rr] += bvals[ni];

    // ---- column partials over this block's 128 rows ----
#pragma unroll
    for (int ni = 0; ni < 2; ++ni) {
        float s = 0.f, q = 0.f;
#pragma unroll
        for (int mi = 0; mi < 2; ++mi)
#pragma unroll
            for (int rr = 0; rr < 4; ++rr) {
                const float v = acc[mi][ni][rr];
                s += v; q += v * v;
            }
        s += __shfl_xor(s, 16); s += __shfl_xor(s, 32);   // over 4 quads = 32 rows
        q += __shfl_xor(q, 16); q += __shfl_xor(q, 32);
        if (quad == 0) {
            Sred[wr][wc * 32 + ni * 16 + lam] = s;
            Qred[wr][wc * 32 + ni * 16 + lam] = q;
        }
    }
    __syncthreads();

    if (tid < 128) {
        float s = 0.f, q = 0.f;
#pragma unroll
        for (int w = 0; w < 4; ++w) { s += Sred[w][tid]; q += Qred[w][tid]; }
        psum[(o * 4 + bt) * 128 + tid] = s;
        psq [(o * 4 + bt) * 128 + tid] = q;
    }

    __threadfence();
    cg::this_grid().sync();

    // ---- BN finalize for this o ----
    if (tid < 128) {
        float s = 0.f, q = 0.f;
#pragma unroll
        for (int t = 0; t < 4; ++t) {
            s += psum[(o * 4 + t) * 128 + tid];
            q += psq [(o * 4 + t) * 128 + tid];
        }
        const float mean = s * (1.0f / 512.0f);
        const float var  = q * (1.0f / 512.0f) - mean * mean;
        const float rstd = rsqrtf(var + 1e-5f);
        const float sc   = rstd * gamma[o * 128 + tid];
        sscale[tid] = sc;
        sshift[tid] = beta[o * 128 + tid] - mean * sc;
    }
    __syncthreads();

    // ---- normalize + SiLU in-register, store fp32 ----
#pragma unroll
    for (int mi = 0; mi < 2; ++mi) {
        const int rowb = b0 + wr * 32 + mi * 16 + quad * 4;
#pragma unroll
        for (int ni = 0; ni < 2; ++ni) {
            const int col = wc * 32 + ni * 16 + lam;
            const float sc = sscale[col];
            const float sh = sshift[col];
#pragma unroll
            for (int rr = 0; rr < 4; ++rr) {
                const float xn = acc[mi][ni][rr] * sc + sh;
                const float sg = 1.0f / (1.0f + __expf(-xn));
                out[(rowb + rr) * FEAT + o * 128 + col] = xn * sg;
            }
        }
    }
}

extern "C" void kernel_launch(void* const* d_in, const int* in_sizes, int n_in,
                              void* d_out, int out_size, void* d_ws, size_t ws_size,
                              hipStream_t stream)
{
    const float* x     = (const float*)d_in[0];
    const float* W     = (const float*)d_in[1];
    const float* bias  = (const float*)d_in[2];
    const float* gamma = (const float*)d_in[3];
    const float* beta  = (const float*)d_in[4];
    const int*   idx   = (const int*)d_in[5];
    float* out  = (float*)d_out;
    float* psum = (float*)d_ws;                 // 64*4*128 f32 = 128 KiB
    float* psq  = psum + 64 * 4 * 128;          // 128 KiB

    void* args[] = {&x, &W, &bias, &gamma, &beta, &idx, &out, &psum, &psq};
    hipLaunchCooperativeKernel((const void*)fused_encoder_coop,
                               dim3(256), dim3(1024), args, 0, stream);
}

// Round 5
// 162.933 us; speedup vs baseline: 1.2887x; 1.2887x over previous
//
#include <hip/hip_runtime.h>

// EncoderBlock, fused single kernel, balanced 128x128 tiles, NO grid sync:
//   gather(x, idx) -> per-(o, 128-batch-tile) GEMM (128x128 @ K=512) + bias
//   -> atomicAdd column partials into psum/psq[o] -> per-o 4-block flag
//   barrier (device-scope atomics + s_sleep spin) -> BN finalize -> SiLU.
// Grid 256 blocks x 1024 threads (16 waves, 4/SIMD), REGULAR launch.
// Co-residency guaranteed by resources (36 VGPR / 45KB LDS -> >=2 blocks/CU
// capacity >= grid), so the 4-block spin cannot deadlock.
// K-loop: depth-2 register prefetch, double-buffered LDS, ONE raw s_barrier
// per step (lgkmcnt(0) only -- prefetch loads stay in flight, T4).
// Flags/psum/psq are re-poisoned by the harness each iter -> zeroed by a
// 64KB hipMemsetAsync enqueued in-stream before the kernel (graph-safe).

typedef __attribute__((ext_vector_type(8))) __bf16 bf16x8;
typedef __attribute__((ext_vector_type(4))) __bf16 bf16x4;
typedef __attribute__((ext_vector_type(4))) float  f32x4;

#define FEAT 8192
#define LDA  40              // LDS row stride (bf16): 80B, 16B-aligned

#define PIPE_BARRIER() do { \
    __builtin_amdgcn_sched_barrier(0); \
    asm volatile("s_waitcnt lgkmcnt(0)" ::: "memory"); \
    __builtin_amdgcn_s_barrier(); \
    __builtin_amdgcn_sched_barrier(0); \
} while (0)

__global__ __launch_bounds__(1024, 4)
void fused_encoder_sync(const float* __restrict__ x, const float* __restrict__ W,
                        const float* __restrict__ bias, const float* __restrict__ gamma,
                        const float* __restrict__ beta, const int* __restrict__ idxp,
                        float* __restrict__ out, float* __restrict__ psum,
                        float* __restrict__ psq, unsigned int* __restrict__ flags)
{
    __shared__ alignas(16) __bf16 Alds[2][128 * LDA];   // 2 x 10 KiB
    __shared__ alignas(16) __bf16 Blds[2][128 * LDA];   // 2 x 10 KiB
    __shared__ float Sred[4][128];
    __shared__ float Qred[4][128];
    __shared__ float sscale[128];
    __shared__ float sshift[128];

    // XCD-aware decode: 4 batch-tiles of one o share an XCD (perf heuristic
    // only; correctness uses device-scope atomics).
    const int bid = blockIdx.x;
    const int o   = ((bid >> 5) << 3) | (bid & 7);
    const int bt  = (bid >> 3) & 3;
    const int b0  = bt * 128;

    const int tid  = threadIdx.x;
    const int wave = tid >> 6;          // 0..15
    const int lane = tid & 63;
    const int wr   = wave >> 2;         // 0..3: rows wr*32..+31
    const int wc   = wave & 3;          // 0..3: cols wc*32..+31
    const int lam  = lane & 15;
    const int quad = lane >> 4;

    int rsel[4];
#pragma unroll
    for (int k = 0; k < 4; ++k) rsel[k] = idxp[o * 4 + k];

    const f32x4 zero4 = {0.f, 0.f, 0.f, 0.f};
    f32x4 acc[2][2];
#pragma unroll
    for (int mi = 0; mi < 2; ++mi)
#pragma unroll
        for (int ni = 0; ni < 2; ++ni) acc[mi][ni] = zero4;

    // A staging: 8 threads/row, 4 floats each (128 rows x 32 k)
    const int m_a = tid >> 3;           // 0..127
    const int ca  = (tid & 7) * 4;      // 0..28
    // B staging: 4 k-strided scalars per thread (coalesced over e)
    const int e_b = tid & 127;
    const int dgb = tid >> 7;           // 0..7 -> k-offset dgb*4

    f32x4 sA0, sA1, sB0, sB1;

    auto load_stage = [&](f32x4& SA, f32x4& SB, const int kkc) {
        const int kidx = kkc >> 2;
        const int d0   = (kkc & 3) * 32;
        SA = *(const f32x4*)(x + (((b0 + m_a) * 64 + rsel[kidx]) * 128 + d0 + ca));
        const float* wp = W + (((o * 4 + kidx) * 128 + d0 + dgb * 4) * 128 + e_b);
        f32x4 t;
        t[0] = wp[0]; t[1] = wp[128]; t[2] = wp[256]; t[3] = wp[384];
        SB = t;
    };

    auto store_stage = [&](const f32x4& SA, const f32x4& SB, const int buf) {
        bf16x4 pa, pb;
#pragma unroll
        for (int j = 0; j < 4; ++j) { pa[j] = (__bf16)SA[j]; pb[j] = (__bf16)SB[j]; }
        *(bf16x4*)&Alds[buf][m_a * LDA + ca]       = pa;
        *(bf16x4*)&Blds[buf][e_b * LDA + dgb * 4]  = pb;
    };

    auto compute = [&](const int buf) {
        bf16x8 af[2], bfr[2];
#pragma unroll
        for (int mi = 0; mi < 2; ++mi)
            af[mi] = *(const bf16x8*)&Alds[buf][(wr * 32 + mi * 16 + lam) * LDA + quad * 8];
#pragma unroll
        for (int ni = 0; ni < 2; ++ni)
            bfr[ni] = *(const bf16x8*)&Blds[buf][(wc * 32 + ni * 16 + lam) * LDA + quad * 8];
#pragma unroll
        for (int mi = 0; mi < 2; ++mi)
#pragma unroll
            for (int ni = 0; ni < 2; ++ni)
                acc[mi][ni] = __builtin_amdgcn_mfma_f32_16x16x32_bf16(
                    af[mi], bfr[ni], acc[mi][ni], 0, 0, 0);
    };

    // ---- pipeline: data kk lives in stage/buf (kk & 1) ----
    load_stage(sA0, sB0, 0);
    load_stage(sA1, sB1, 1);
    store_stage(sA0, sB0, 0);   // vmcnt waits stage-0 only; stage-1 in flight
    PIPE_BARRIER();

#pragma unroll
    for (int kk = 0; kk < 16; ++kk) {
        if (kk + 2 < 16) {
            if ((kk & 1) == 0) load_stage(sA0, sB0, kk + 2);
            else               load_stage(sA1, sB1, kk + 2);
        }
        __builtin_amdgcn_sched_barrier(0);
        compute(kk & 1);
        if (kk + 1 < 16) {
            if ((kk & 1) == 0) store_stage(sA1, sB1, 1);
            else               store_stage(sA0, sB0, 0);
            PIPE_BARRIER();
        }
    }

    // ---- bias ----
    float bvals[2];
#pragma unroll
    for (int ni = 0; ni < 2; ++ni)
        bvals[ni] = bias[o * 128 + wc * 32 + ni * 16 + lam];
#pragma unroll
    for (int mi = 0; mi < 2; ++mi)
#pragma unroll
        for (int ni = 0; ni < 2; ++ni)
#pragma unroll
            for (int rr = 0; rr < 4; ++rr) acc[mi][ni][rr] += bvals[ni];

    // ---- column partials over this block's 128 rows ----
#pragma unroll
    for (int ni = 0; ni < 2; ++ni) {
        float s = 0.f, q = 0.f;
#pragma unroll
        for (int mi = 0; mi < 2; ++mi)
#pragma unroll
            for (int rr = 0; rr < 4; ++rr) {
                const float v = acc[mi][ni][rr];
                s += v; q += v * v;
            }
        s += __shfl_xor(s, 16); s += __shfl_xor(s, 32);   // over 4 quads = 32 rows
        q += __shfl_xor(q, 16); q += __shfl_xor(q, 32);
        if (quad == 0) {
            Sred[wr][wc * 32 + ni * 16 + lam] = s;
            Qred[wr][wc * 32 + ni * 16 + lam] = q;
        }
    }
    __syncthreads();

    // ---- accumulate into per-o stats (device-coherent RMW) ----
    if (tid < 128) {
        float s = 0.f, q = 0.f;
#pragma unroll
        for (int w = 0; w < 4; ++w) { s += Sred[w][tid]; q += Qred[w][tid]; }
        atomicAdd(&psum[o * 128 + tid], s);
        atomicAdd(&psq [o * 128 + tid], q);
    }
    __threadfence();          // release: partials globally visible before flag
    __syncthreads();

    // ---- per-o 4-block barrier ----
    if (tid == 0) {
        __hip_atomic_fetch_add(&flags[o], 1u, __ATOMIC_ACQ_REL,
                               __HIP_MEMORY_SCOPE_AGENT);
        while (__hip_atomic_load(&flags[o], __ATOMIC_ACQUIRE,
                                 __HIP_MEMORY_SCOPE_AGENT) < 4u)
            __builtin_amdgcn_s_sleep(2);
    }
    __syncthreads();

    // ---- BN finalize (AGENT-scope loads: cache-coherent read of partials) ----
    if (tid < 128) {
        const float s = __hip_atomic_load(&psum[o * 128 + tid], __ATOMIC_RELAXED,
                                          __HIP_MEMORY_SCOPE_AGENT);
        const float q = __hip_atomic_load(&psq[o * 128 + tid], __ATOMIC_RELAXED,
                                          __HIP_MEMORY_SCOPE_AGENT);
        const float mean = s * (1.0f / 512.0f);
        const float var  = q * (1.0f / 512.0f) - mean * mean;
        const float rstd = rsqrtf(var + 1e-5f);
        const float sc   = rstd * gamma[o * 128 + tid];
        sscale[tid] = sc;
        sshift[tid] = beta[o * 128 + tid] - mean * sc;
    }
    __syncthreads();

    // ---- normalize + SiLU in-register, store fp32 ----
#pragma unroll
    for (int mi = 0; mi < 2; ++mi) {
        const int rowb = b0 + wr * 32 + mi * 16 + quad * 4;
#pragma unroll
        for (int ni = 0; ni < 2; ++ni) {
            const int col = wc * 32 + ni * 16 + lam;
            const float sc = sscale[col];
            const float sh = sshift[col];
#pragma unroll
            for (int rr = 0; rr < 4; ++rr) {
                const float xn = acc[mi][ni][rr] * sc + sh;
                const float sg = 1.0f / (1.0f + __expf(-xn));
                out[(rowb + rr) * FEAT + o * 128 + col] = xn * sg;
            }
        }
    }
}

extern "C" void kernel_launch(void* const* d_in, const int* in_sizes, int n_in,
                              void* d_out, int out_size, void* d_ws, size_t ws_size,
                              hipStream_t stream)
{
    const float* x     = (const float*)d_in[0];
    const float* W     = (const float*)d_in[1];
    const float* bias  = (const float*)d_in[2];
    const float* gamma = (const float*)d_in[3];
    const float* beta  = (const float*)d_in[4];
    const int*   idx   = (const int*)d_in[5];
    float* out  = (float*)d_out;

    float* psum = (float*)d_ws;                       // 64*128 f32 = 32 KiB
    float* psq  = psum + 64 * 128;                    // 32 KiB
    unsigned int* flags = (unsigned int*)(psq + 64 * 128);  // 256 B

    // zero psum/psq/flags (harness re-poisons ws each iteration)
    hipMemsetAsync(d_ws, 0, (size_t)(64 * 128 * 4 * 2 + 64 * 4), stream);

    fused_encoder_sync<<<dim3(256), dim3(1024), 0, stream>>>(
        x, W, bias, gamma, beta, idx, out, psum, psq, flags);
}

// Round 6
// 114.376 us; speedup vs baseline: 1.8357x; 1.4245x over previous
//
#include <hip/hip_runtime.h>

// EncoderBlock, fused single kernel, BN block-local, A DIRECT-TO-REGISTER:
//   gather(x, idx) -> GEMM slice (M=512 batches x N=32 cols @ K=512) + bias
//   -> BN stats over the block's own 512 rows -> SiLU -> fp32 out.
// Grid: 256 blocks = (o, 32-col slice) x 1024 threads (16 waves, 4/SIMD).
// A fragments are wave-private rows with k-contiguous floats in x -> loaded
// straight to registers (depth-2 pipeline), NO A LDS staging. Only the tiny
// 32x32 B tile goes through LDS (double-buffered, one raw s_barrier/step,
// lgkmcnt(0) only -- global prefetch loads stay in flight across barriers).
// No cross-block sync of any kind (rounds 2/4/5 showed it costs 50-80us).

typedef __attribute__((ext_vector_type(8))) __bf16 bf16x8;
typedef __attribute__((ext_vector_type(4))) float  f32x4;

#define FEAT 8192
#define XROW 8192            // N_IN * D_IN floats per batch row of x
#define LDB  40              // B LDS row stride (bf16): 80B, 16B-aligned

#define PIPE_BARRIER() do { \
    __builtin_amdgcn_sched_barrier(0); \
    asm volatile("s_waitcnt lgkmcnt(0)" ::: "memory"); \
    __builtin_amdgcn_s_barrier(); \
    __builtin_amdgcn_sched_barrier(0); \
} while (0)

__global__ __launch_bounds__(1024, 4)
void fused_encoder(const float* __restrict__ x, const float* __restrict__ W,
                   const float* __restrict__ bias, const float* __restrict__ gamma,
                   const float* __restrict__ beta, const int* __restrict__ idxp,
                   float* __restrict__ out)
{
    __shared__ alignas(16) __bf16 Blds[2][32 * LDB];    // 2 x 2.5 KiB
    __shared__ float Sred[16][32];
    __shared__ float Qred[16][32];
    __shared__ float sscale[32];
    __shared__ float sshift[32];

    // XCD-aware decode: 4 col-slices of one o share an XCD (shared gathered-A
    // panel stays L2-resident; perf heuristic only).
    const int bid = blockIdx.x;
    const int o   = ((bid >> 5) << 3) | (bid & 7);
    const int es  = (bid >> 3) & 3;
    const int e0  = es * 32;

    const int tid  = threadIdx.x;
    const int wave = tid >> 6;          // 0..15 -> rows wave*32 .. +31
    const int lane = tid & 63;
    const int lam  = lane & 15;
    const int quad = lane >> 4;

    int rsel[4];
#pragma unroll
    for (int k = 0; k < 4; ++k) rsel[k] = idxp[o * 4 + k];

    const f32x4 zero4 = {0.f, 0.f, 0.f, 0.f};
    f32x4 acc[2][2];
#pragma unroll
    for (int mi = 0; mi < 2; ++mi)
#pragma unroll
        for (int ni = 0; ni < 2; ++ni) acc[mi][ni] = zero4;

    // A: per-lane row bases for the two fragments (rows wave*32+lam, +16)
    const float* xrow0 = x + (wave * 32 + lam)      * XROW;
    const float* xrow1 = x + (wave * 32 + 16 + lam) * XROW;

    // B staging map: 1 float/thread (32 e x 32 k)
    const int e_b = tid & 31;
    const int d_b = tid >> 5;           // 0..31

    // register pipeline stages (named, statically indexed)
    f32x4 sa0[4], sa1[4];               // A raw floats: [0..1]=frag0, [2..3]=frag1
    float sb0, sb1;                     // B raw float

    auto loadA = [&](f32x4 (&SA)[4], const int kkc) {
        const int r  = rsel[kkc >> 2];
        const int dd = (kkc & 3) * 32 + quad * 8;
        const float* p0 = xrow0 + r * 128 + dd;
        const float* p1 = xrow1 + r * 128 + dd;
        SA[0] = *(const f32x4*)(p0);
        SA[1] = *(const f32x4*)(p0 + 4);
        SA[2] = *(const f32x4*)(p1);
        SA[3] = *(const f32x4*)(p1 + 4);
    };
    auto loadB = [&](float& SB, const int kkc) {
        const int kidx = kkc >> 2;
        const int d0   = (kkc & 3) * 32;
        SB = W[(((o * 4 + kidx) * 128) + d0 + d_b) * 128 + e0 + e_b];
    };
    auto storeB = [&](const float SB, const int buf) {
        Blds[buf][e_b * LDB + d_b] = (__bf16)SB;
    };
    auto cvtA = [&](const f32x4 (&SA)[4], bf16x8 (&af)[2]) {
#pragma unroll
        for (int j = 0; j < 4; ++j) {
            af[0][j]     = (__bf16)SA[0][j];
            af[0][j + 4] = (__bf16)SA[1][j];
            af[1][j]     = (__bf16)SA[2][j];
            af[1][j + 4] = (__bf16)SA[3][j];
        }
    };
    auto mma = [&](const bf16x8 (&af)[2], const int buf) {
        bf16x8 bfr[2];
#pragma unroll
        for (int ni = 0; ni < 2; ++ni)
            bfr[ni] = *(const bf16x8*)&Blds[buf][(ni * 16 + lam) * LDB + quad * 8];
#pragma unroll
        for (int mi = 0; mi < 2; ++mi)
#pragma unroll
            for (int ni = 0; ni < 2; ++ni)
                acc[mi][ni] = __builtin_amdgcn_mfma_f32_16x16x32_bf16(
                    af[mi], bfr[ni], acc[mi][ni], 0, 0, 0);
    };

    // ---- prologue ----
    loadA(sa0, 0); loadB(sb0, 0);
    loadA(sa1, 1); loadB(sb1, 1);
    storeB(sb0, 0);             // waits vmcnt for sb0 chain; stage-1 in flight
    PIPE_BARRIER();

#pragma unroll
    for (int kk = 0; kk < 16; ++kk) {
        bf16x8 af[2];
        if ((kk & 1) == 0) {
            cvtA(sa0, af);                         // consumes A(kk): stage free
            if (kk + 2 < 16) { loadA(sa0, kk + 2); loadB(sb0, kk + 2); }
        } else {
            cvtA(sa1, af);
            if (kk + 2 < 16) { loadA(sa1, kk + 2); loadB(sb1, kk + 2); }
        }
        __builtin_amdgcn_sched_barrier(0);         // loads issued before mma
        mma(af, kk & 1);
        if (kk + 1 < 16) {                         // stage B(kk+1) -> buf (kk+1)&1
            if ((kk & 1) == 0) storeB(sb1, 1);
            else               storeB(sb0, 0);
            PIPE_BARRIER();
        }
    }

    // ---- bias ----
    float bvals[2];
#pragma unroll
    for (int ni = 0; ni < 2; ++ni)
        bvals[ni] = bias[o * 128 + e0 + ni * 16 + lam];
#pragma unroll
    for (int mi = 0; mi < 2; ++mi)
#pragma unroll
        for (int ni = 0; ni < 2; ++ni)
#pragma unroll
            for (int rr = 0; rr < 4; ++rr) acc[mi][ni][rr] += bvals[ni];

    // ---- BN stats: block-local (block owns all 512 rows of its 32 cols) ----
#pragma unroll
    for (int ni = 0; ni < 2; ++ni) {
        float s = 0.f, q = 0.f;
#pragma unroll
        for (int mi = 0; mi < 2; ++mi)
#pragma unroll
            for (int rr = 0; rr < 4; ++rr) {
                const float v = acc[mi][ni][rr];
                s += v; q += v * v;
            }
        s += __shfl_xor(s, 16); s += __shfl_xor(s, 32);
        q += __shfl_xor(q, 16); q += __shfl_xor(q, 32);
        if (quad == 0) {
            Sred[wave][ni * 16 + lam] = s;
            Qred[wave][ni * 16 + lam] = q;
        }
    }
    __syncthreads();

    if (tid < 32) {
        float s = 0.f, q = 0.f;
#pragma unroll
        for (int w = 0; w < 16; ++w) {
            s += Sred[w][tid];
            q += Qred[w][tid];
        }
        const float mean = s * (1.0f / 512.0f);
        const float var  = q * (1.0f / 512.0f) - mean * mean;
        const float rstd = rsqrtf(var + 1e-5f);
        const float sc   = rstd * gamma[o * 128 + e0 + tid];
        sscale[tid] = sc;
        sshift[tid] = beta[o * 128 + e0 + tid] - mean * sc;
    }
    __syncthreads();

    // ---- normalize + SiLU in-register, store fp32 ----
#pragma unroll
    for (int mi = 0; mi < 2; ++mi) {
        const int rowb = wave * 32 + mi * 16 + quad * 4;
#pragma unroll
        for (int ni = 0; ni < 2; ++ni) {
            const int col = ni * 16 + lam;
            const float sc = sscale[col];
            const float sh = sshift[col];
#pragma unroll
            for (int rr = 0; rr < 4; ++rr) {
                const float xn = acc[mi][ni][rr] * sc + sh;
                const float sg = 1.0f / (1.0f + __expf(-xn));
                out[(rowb + rr) * FEAT + o * 128 + e0 + col] = xn * sg;
            }
        }
    }
}

extern "C" void kernel_launch(void* const* d_in, const int* in_sizes, int n_in,
                              void* d_out, int out_size, void* d_ws, size_t ws_size,
                              hipStream_t stream)
{
    const float* x     = (const float*)d_in[0];
    const float* W     = (const float*)d_in[1];
    const float* bias  = (const float*)d_in[2];
    const float* gamma = (const float*)d_in[3];
    const float* beta  = (const float*)d_in[4];
    const int*   idx   = (const int*)d_in[5];
    float* out = (float*)d_out;

    fused_encoder<<<dim3(256), dim3(1024), 0, stream>>>(
        x, W, bias, gamma, beta, idx, out);
}